// Round 15
// baseline (389.683 us; speedup 1.0000x reference)
//
#include <hip/hip_runtime.h>

// WaveRNN: damped 2D wave equation, B=16, T=256, 256x256 grid, 3 probes.
// Structure = R11 champion (337us), byte-identical protocol, ONE delta:
//   Seam waves publish their seam row IMMEDIATELY after computing it:
//   poll -> ROWC(seam row) -> SRCP -> GPUB (fire-and-forget) -> other
//   boundary row -> LDS publish -> interiors. R11 computed both boundary
//   rows + LDS publish before GPUB; that put ~200cy of work between
//   poll-success and the global publish on the seam critical path.
//   (R13 lesson: anything placed BEFORE the poll or between poll and
//   publish lengthens the skew-1 rendezvous period. Publish-ASAP only.)
// Protocol recap: wave w owns rows s*32+4w..+3, lane l cols 4l..4l+3.
// NO __syncthreads in the main loop. Intra-WG: per-substep tagged LDS rows
// (vals -> lgkmcnt(0) -> tag; in-order DS => tag-visible implies vals-
// visible), parity double-buffered. Inter-WG: tagged 8-byte {step,value}
// packets, relaxed agent-scope atomics, parity double-buffered. Skew bounded
// to 1 step by the mutual stencil dependency (proves no overwrite-before-
// read and no deadlock). XCD colocation kept (neutral, but free).

#define B_    16
#define T_    256
#define NY    256
#define NP    3
#define NSLAB 8
#define WAVES 8
#define THREADS 512
#define NIF   (NSLAB - 1)

// [side][batch][iface][parity][j][lane]
// side0: slab i's bottom row (wave7 row3) -> consumed by slab i+1 (up ghost)
// side1: slab i+1's top row (wave0 row0)  -> consumed by slab i (down ghost)
__device__ uint64_t g_halo[2][B_][NIF][2][4][64];

__global__ void reset_halo()
{
    const int n = 2 * B_ * NIF * 2 * 4 * 64;
    int i = blockIdx.x * blockDim.x + threadIdx.x;
    if (i < n) (&g_halo[0][0][0][0][0][0])[i] = 0ull;   // tag0,val0 = step-0 data
}

#define PACK(tag, f) (((uint64_t)(uint32_t)(tag) << 32) | (uint64_t)__float_as_uint(f))

#define GPOLL(dst, side, iface, P_, TT) do { \
    uint64_t* gp_ = &g_halo[side][b][iface][P_][0][l]; \
    uint64_t a0_, a1_, a2_, a3_; bool ok_; bool first_ = true; \
    do { \
        if (!first_) __builtin_amdgcn_s_sleep(1); \
        first_ = false; \
        a0_ = __hip_atomic_load(gp_ + 0 * 64, __ATOMIC_RELAXED, __HIP_MEMORY_SCOPE_AGENT); \
        a1_ = __hip_atomic_load(gp_ + 1 * 64, __ATOMIC_RELAXED, __HIP_MEMORY_SCOPE_AGENT); \
        a2_ = __hip_atomic_load(gp_ + 2 * 64, __ATOMIC_RELAXED, __HIP_MEMORY_SCOPE_AGENT); \
        a3_ = __hip_atomic_load(gp_ + 3 * 64, __ATOMIC_RELAXED, __HIP_MEMORY_SCOPE_AGENT); \
        ok_ = ((uint32_t)(a0_ >> 32) == (uint32_t)(TT)) && ((uint32_t)(a1_ >> 32) == (uint32_t)(TT)) \
           && ((uint32_t)(a2_ >> 32) == (uint32_t)(TT)) && ((uint32_t)(a3_ >> 32) == (uint32_t)(TT)); \
    } while (!ok_); \
    dst[0] = __uint_as_float((uint32_t)a0_); dst[1] = __uint_as_float((uint32_t)a1_); \
    dst[2] = __uint_as_float((uint32_t)a2_); dst[3] = __uint_as_float((uint32_t)a3_); \
} while (0)

#define GPUB(side, iface, Q_, TAG1, HROW) do { \
    uint64_t* gp_ = &g_halo[side][b][iface][Q_][0][l]; \
    __hip_atomic_store(gp_ + 0 * 64, PACK(TAG1, HROW[0]), __ATOMIC_RELAXED, __HIP_MEMORY_SCOPE_AGENT); \
    __hip_atomic_store(gp_ + 1 * 64, PACK(TAG1, HROW[1]), __ATOMIC_RELAXED, __HIP_MEMORY_SCOPE_AGENT); \
    __hip_atomic_store(gp_ + 2 * 64, PACK(TAG1, HROW[2]), __ATOMIC_RELAXED, __HIP_MEMORY_SCOPE_AGENT); \
    __hip_atomic_store(gp_ + 3 * 64, PACK(TAG1, HROW[3]), __ATOMIC_RELAXED, __HIP_MEMORY_SCOPE_AGENT); \
} while (0)

// hn = h2 + TC*(h1-h2) + CC*(s4 - 4*h1), written into H2[r] in place.
#define ROWC(H1, H2, r, UPA, DNA) do { \
    float lf_ = __shfl_up(H1[r][3], 1, 64); \
    float rt_ = __shfl_down(H1[r][0], 1, 64); \
    if (l == 0)  lf_ = 0.f; \
    if (l == 63) rt_ = 0.f; \
    _Pragma("unroll") for (int j = 0; j < 4; ++j) { \
        const float lv_ = (j == 0) ? lf_ : H1[r][j - 1]; \
        const float rv_ = (j == 3) ? rt_ : H1[r][j + 1]; \
        const float s4_ = (UPA[j] + DNA[j]) + (lv_ + rv_); \
        const float d_  = H1[r][j] - H2[r][j]; \
        const float e_  = fmaf(-4.0f, H1[r][j], s4_); \
        float v_ = fmaf(CC[r][j], e_, H2[r][j]); \
        v_ = fmaf(TC[r][j], d_, v_); \
        H2[r][j] = v_; \
    } \
} while (0)

#define SRCP(H2, r, TT) do { \
    if (srcHere && src_r == (r)) { \
        _Pragma("unroll") for (int j = 0; j < 4; ++j) \
            if (src_c == j) H2[r][j] += xbuf[TT]; \
    } \
    _Pragma("unroll") for (int qq = 0; qq < NP; ++qq) { \
        if (pHere[qq] && pr[qq] == (r)) { \
            float v_ = 0.f; \
            _Pragma("unroll") for (int j = 0; j < 4; ++j) \
                if (pc[qq] == j) v_ = H2[r][j]; \
            out[((size_t)b * T_ + (TT)) * NP + qq] = v_; \
        } \
    } \
} while (0)

// One substep: H1=h^t, H2=h^{t-1} -> h^{t+1} into H2. P_=t&1, Q_=(t+1)&1.
// Seam waves: poll -> seam row -> GPUB ASAP -> other row -> LDS publish ->
// interiors. Non-seam: R11 order.
#define SUB(H1, H2, TT, P_, Q_) do { \
    float gu_[4], gd_[4]; \
    if (w == 0) { \
        if (s == 0) { gu_[0] = gu_[1] = gu_[2] = gu_[3] = 0.f; } \
        else GPOLL(gu_, 0, s - 1, P_, TT); \
    } else { \
        while (__hip_atomic_load(&r3t[w - 1][P_], __ATOMIC_RELAXED, __HIP_MEMORY_SCOPE_WORKGROUP) != (TT)) {} \
        asm volatile("" ::: "memory"); \
        const float4 u4_ = *reinterpret_cast<const float4*>(&r3v[w - 1][P_][y0]); \
        gu_[0] = u4_.x; gu_[1] = u4_.y; gu_[2] = u4_.z; gu_[3] = u4_.w; \
    } \
    if (w == WAVES - 1) { \
        if (s == NSLAB - 1) { gd_[0] = gd_[1] = gd_[2] = gd_[3] = 0.f; } \
        else GPOLL(gd_, 1, s, P_, TT); \
    } else { \
        while (__hip_atomic_load(&r0t[w + 1][P_], __ATOMIC_RELAXED, __HIP_MEMORY_SCOPE_WORKGROUP) != (TT)) {} \
        asm volatile("" ::: "memory"); \
        const float4 d4_ = *reinterpret_cast<const float4*>(&r0v[w + 1][P_][y0]); \
        gd_[0] = d4_.x; gd_[1] = d4_.y; gd_[2] = d4_.z; gd_[3] = d4_.w; \
    } \
    if (w == 0 && s > 0) { \
        /* up-seam: seam row 0 first, publish immediately */ \
        ROWC(H1, H2, 0, gu_, H1[1]); \
        SRCP(H2, 0, TT); \
        GPUB(1, s - 1, Q_, (TT) + 1, H2[0]); \
        ROWC(H1, H2, 3, H1[2], gd_); \
        SRCP(H2, 3, TT); \
    } else if (w == WAVES - 1 && s < NSLAB - 1) { \
        /* dn-seam: seam row 3 first, publish immediately */ \
        ROWC(H1, H2, 3, H1[2], gd_); \
        SRCP(H2, 3, TT); \
        GPUB(0, s, Q_, (TT) + 1, H2[3]); \
        ROWC(H1, H2, 0, gu_, H1[1]); \
        SRCP(H2, 0, TT); \
    } else { \
        ROWC(H1, H2, 0, gu_, H1[1]); \
        ROWC(H1, H2, 3, H1[2], gd_); \
        SRCP(H2, 0, TT); \
        SRCP(H2, 3, TT); \
    } \
    /* publish: vals, drain DS, then tags (in-order DS => tag implies vals) */ \
    if (w > 0) \
        *reinterpret_cast<float4*>(&r0v[w][Q_][y0]) = make_float4(H2[0][0], H2[0][1], H2[0][2], H2[0][3]); \
    if (w < WAVES - 1) \
        *reinterpret_cast<float4*>(&r3v[w][Q_][y0]) = make_float4(H2[3][0], H2[3][1], H2[3][2], H2[3][3]); \
    asm volatile("s_waitcnt lgkmcnt(0)" ::: "memory"); \
    if (l == 0) { \
        if (w > 0) \
            __hip_atomic_store(&r0t[w][Q_], (TT) + 1, __ATOMIC_RELAXED, __HIP_MEMORY_SCOPE_WORKGROUP); \
        if (w < WAVES - 1) \
            __hip_atomic_store(&r3t[w][Q_], (TT) + 1, __ATOMIC_RELAXED, __HIP_MEMORY_SCOPE_WORKGROUP); \
    } \
    /* interior rows overlap neighbors' consumption */ \
    ROWC(H1, H2, 1, H1[0], H1[2]); \
    ROWC(H1, H2, 2, H1[1], H1[3]); \
    SRCP(H2, 1, TT); \
    SRCP(H2, 2, TT); \
} while (0)

__launch_bounds__(THREADS, 2)
__global__ void wave_multi(const float* __restrict__ xin,
                           const float* __restrict__ cin,
                           const float* __restrict__ bin,
                           const int* __restrict__ pxp,
                           const int* __restrict__ pyp,
                           const int* __restrict__ sxp,
                           const int* __restrict__ syp,
                           float* __restrict__ out)
{
    const int blk = blockIdx.x;
    // XCD colocation: blk%8 = XCD (round-robin dispatch). All slabs of a
    // batch on one XCD: b%8 == blk%8.
    const int xcd = blk & 7;
    const int m   = blk >> 3;         // 0..15
    const int s   = m & 7;            // slab: rows [s*32, s*32+32)
    const int b   = xcd + ((m >> 3) << 3);  // batch
    const int tid = threadIdx.x;
    const int w = tid >> 6;           // wave 0..7
    const int l = tid & 63;           // lane
    const int r0 = s * 32 + w * 4;    // global row of tile row 0
    const int y0 = l * 4;             // global col of tile col 0

    __shared__ float xbuf[T_];
    __shared__ float r0v[WAVES][2][NY];   // wave w's row0 values, by parity
    __shared__ float r3v[WAVES][2][NY];   // wave w's row3 values, by parity
    __shared__ int   r0t[WAVES][2];       // tags
    __shared__ int   r3t[WAVES][2];

    for (int i = tid; i < WAVES * 2 * NY; i += THREADS) {
        (&r0v[0][0][0])[i] = 0.f;
        (&r3v[0][0][0])[i] = 0.f;
    }
    if (tid < WAVES * 2) {
        const int w_ = tid >> 1, p_ = tid & 1;
        r0t[w_][p_] = (p_ == 0) ? 0 : -1;   // parity0 holds valid step-0 zeros
        r3t[w_][p_] = (p_ == 0) ? 0 : -1;
    }
    if (tid < T_) xbuf[tid] = xin[b * T_ + tid];

    // state + compressed coefficients: TC = 2*c1, CC = c1*(DT^2*c^2)
    // hn = h2 + TC*(h1-h2) + CC*(s4 - 4*h1)   [c1*c2 == 2*c1 - 1]
    float h1[4][4], h2[4][4], TC[4][4], CC[4][4];
#pragma unroll
    for (int r = 0; r < 4; ++r) {
        const float4 cv = *reinterpret_cast<const float4*>(&cin[(r0 + r) * NY + y0]);
        const float4 bv = *reinterpret_cast<const float4*>(&bin[(r0 + r) * NY + y0]);
        const float cvv[4] = {cv.x, cv.y, cv.z, cv.w};
        const float bvv[4] = {bv.x, bv.y, bv.z, bv.w};
#pragma unroll
        for (int j = 0; j < 4; ++j) {
            const float c1  = 1.0f / (1.0f + 0.25f * bvv[j]);
            const float csq = 0.25f * cvv[j] * cvv[j];
            TC[r][j] = 2.0f * c1;
            CC[r][j] = c1 * csq;
            h1[r][j] = 0.f;
            h2[r][j] = 0.f;
        }
    }

    const int sx = sxp[0], sy = syp[0];
    const bool srcHere = (sx >= r0 && sx < r0 + 4 && sy >= y0 && sy < y0 + 4);
    const int  src_r = sx - r0, src_c = sy - y0;
    bool pHere[NP];
    int  pr[NP], pc[NP];
#pragma unroll
    for (int q = 0; q < NP; ++q) {
        const int pxx = pxp[q], pyy = pyp[q];
        pHere[q] = (pxx >= r0 && pxx < r0 + 4 && pyy >= y0 && pyy < y0 + 4);
        pr[q] = pxx - r0;
        pc[q] = pyy - y0;
    }

    __syncthreads();   // the only barrier: LDS init

#pragma unroll 1
    for (int t = 0; t < T_; t += 2) {
        SUB(h1, h2, t,     0, 1);   // h^{t+1} -> h2
        SUB(h2, h1, t + 1, 1, 0);   // h^{t+2} -> h1
    }
}

extern "C" void kernel_launch(void* const* d_in, const int* in_sizes, int n_in,
                              void* d_out, int out_size, void* d_ws, size_t ws_size,
                              hipStream_t stream)
{
    const float* x  = (const float*)d_in[0];
    const float* c  = (const float*)d_in[1];
    const float* bb = (const float*)d_in[2];
    const int*   px = (const int*)d_in[3];
    const int*   py = (const int*)d_in[4];
    const int*   sx = (const int*)d_in[5];
    const int*   sy = (const int*)d_in[6];
    float* out = (float*)d_out;

    const int words = 2 * B_ * NIF * 2 * 4 * 64;
    reset_halo<<<(words + 255) / 256, 256, 0, stream>>>();

    void* args[] = { (void*)&x, (void*)&c, (void*)&bb, (void*)&px, (void*)&py,
                     (void*)&sx, (void*)&sy, (void*)&out };
    hipLaunchCooperativeKernel(reinterpret_cast<void*>(wave_multi),
                               dim3(B_ * NSLAB), dim3(THREADS), args, 0, stream);
}

// Round 16
// 358.195 us; speedup vs baseline: 1.0879x; 1.0879x over previous
//
#include <hip/hip_runtime.h>

// WaveRNN: damped 2D wave equation, B=16, T=256, 256x256 grid, 3 probes.
// CHAMPION (R11, 337us) restored byte-for-byte. Structure:
//   - 8 slabs/batch (128 WGs x 512 thr, cooperative). Wave w owns rows
//     s*32+4w..+3, lane l cols 4l..4l+3 (4x4 register tile).
//   - NO __syncthreads in the main loop. Intra-WG: per-substep tagged LDS
//     rows (vals -> lgkmcnt(0) -> tag; in-order DS => tag-visible implies
//     vals-visible), parity double-buffered.
//   - Inter-WG: tagged 8-byte {step,value} packets, relaxed agent-scope
//     atomics, parity double-buffered. s_sleep(1) backoff in seam polls.
//   - Skew bounded to 1 step by the mutual stencil dependency (proves no
//     overwrite-before-read and no deadlock).
//   - XCD colocation: all 8 slabs of a batch on one XCD (neutral, free).
// Period model (verified +-2%): 1.32us/step = 0.25 compute + 1.05 agent-
// scope publish->detect RT. Falsified levers: temporal blocking (R3,R5-R10),
// L2 transport (R12), placement (R11), ordering perms (R13,R14).

#define B_    16
#define T_    256
#define NY    256
#define NP    3
#define NSLAB 8
#define WAVES 8
#define THREADS 512
#define NIF   (NSLAB - 1)

// [side][batch][iface][parity][j][lane]
// side0: slab i's bottom row (wave7 row3) -> consumed by slab i+1 (up ghost)
// side1: slab i+1's top row (wave0 row0)  -> consumed by slab i (down ghost)
__device__ uint64_t g_halo[2][B_][NIF][2][4][64];

__global__ void reset_halo()
{
    const int n = 2 * B_ * NIF * 2 * 4 * 64;
    int i = blockIdx.x * blockDim.x + threadIdx.x;
    if (i < n) (&g_halo[0][0][0][0][0][0])[i] = 0ull;   // tag0,val0 = step-0 data
}

#define PACK(tag, f) (((uint64_t)(uint32_t)(tag) << 32) | (uint64_t)__float_as_uint(f))

#define GPOLL(dst, side, iface, P_, TT) do { \
    uint64_t* gp_ = &g_halo[side][b][iface][P_][0][l]; \
    uint64_t a0_, a1_, a2_, a3_; bool ok_; bool first_ = true; \
    do { \
        if (!first_) __builtin_amdgcn_s_sleep(1); \
        first_ = false; \
        a0_ = __hip_atomic_load(gp_ + 0 * 64, __ATOMIC_RELAXED, __HIP_MEMORY_SCOPE_AGENT); \
        a1_ = __hip_atomic_load(gp_ + 1 * 64, __ATOMIC_RELAXED, __HIP_MEMORY_SCOPE_AGENT); \
        a2_ = __hip_atomic_load(gp_ + 2 * 64, __ATOMIC_RELAXED, __HIP_MEMORY_SCOPE_AGENT); \
        a3_ = __hip_atomic_load(gp_ + 3 * 64, __ATOMIC_RELAXED, __HIP_MEMORY_SCOPE_AGENT); \
        ok_ = ((uint32_t)(a0_ >> 32) == (uint32_t)(TT)) && ((uint32_t)(a1_ >> 32) == (uint32_t)(TT)) \
           && ((uint32_t)(a2_ >> 32) == (uint32_t)(TT)) && ((uint32_t)(a3_ >> 32) == (uint32_t)(TT)); \
    } while (!ok_); \
    dst[0] = __uint_as_float((uint32_t)a0_); dst[1] = __uint_as_float((uint32_t)a1_); \
    dst[2] = __uint_as_float((uint32_t)a2_); dst[3] = __uint_as_float((uint32_t)a3_); \
} while (0)

#define GPUB(side, iface, Q_, TAG1, HROW) do { \
    uint64_t* gp_ = &g_halo[side][b][iface][Q_][0][l]; \
    __hip_atomic_store(gp_ + 0 * 64, PACK(TAG1, HROW[0]), __ATOMIC_RELAXED, __HIP_MEMORY_SCOPE_AGENT); \
    __hip_atomic_store(gp_ + 1 * 64, PACK(TAG1, HROW[1]), __ATOMIC_RELAXED, __HIP_MEMORY_SCOPE_AGENT); \
    __hip_atomic_store(gp_ + 2 * 64, PACK(TAG1, HROW[2]), __ATOMIC_RELAXED, __HIP_MEMORY_SCOPE_AGENT); \
    __hip_atomic_store(gp_ + 3 * 64, PACK(TAG1, HROW[3]), __ATOMIC_RELAXED, __HIP_MEMORY_SCOPE_AGENT); \
} while (0)

// hn = h2 + TC*(h1-h2) + CC*(s4 - 4*h1), written into H2[r] in place.
#define ROWC(H1, H2, r, UPA, DNA) do { \
    float lf_ = __shfl_up(H1[r][3], 1, 64); \
    float rt_ = __shfl_down(H1[r][0], 1, 64); \
    if (l == 0)  lf_ = 0.f; \
    if (l == 63) rt_ = 0.f; \
    _Pragma("unroll") for (int j = 0; j < 4; ++j) { \
        const float lv_ = (j == 0) ? lf_ : H1[r][j - 1]; \
        const float rv_ = (j == 3) ? rt_ : H1[r][j + 1]; \
        const float s4_ = (UPA[j] + DNA[j]) + (lv_ + rv_); \
        const float d_  = H1[r][j] - H2[r][j]; \
        const float e_  = fmaf(-4.0f, H1[r][j], s4_); \
        float v_ = fmaf(CC[r][j], e_, H2[r][j]); \
        v_ = fmaf(TC[r][j], d_, v_); \
        H2[r][j] = v_; \
    } \
} while (0)

#define SRCP(H2, r, TT) do { \
    if (srcHere && src_r == (r)) { \
        _Pragma("unroll") for (int j = 0; j < 4; ++j) \
            if (src_c == j) H2[r][j] += xbuf[TT]; \
    } \
    _Pragma("unroll") for (int qq = 0; qq < NP; ++qq) { \
        if (pHere[qq] && pr[qq] == (r)) { \
            float v_ = 0.f; \
            _Pragma("unroll") for (int j = 0; j < 4; ++j) \
                if (pc[qq] == j) v_ = H2[r][j]; \
            out[((size_t)b * T_ + (TT)) * NP + qq] = v_; \
        } \
    } \
} while (0)

// One substep: H1=h^t, H2=h^{t-1} -> h^{t+1} into H2. P_=t&1, Q_=(t+1)&1.
// Order: poll ghosts -> boundary rows 0,3 -> publish (LDS + global) ->
// interior rows 1,2 (overlap neighbors' consumption).
#define SUB(H1, H2, TT, P_, Q_) do { \
    float gu_[4], gd_[4]; \
    if (w == 0) { \
        if (s == 0) { gu_[0] = gu_[1] = gu_[2] = gu_[3] = 0.f; } \
        else GPOLL(gu_, 0, s - 1, P_, TT); \
    } else { \
        while (__hip_atomic_load(&r3t[w - 1][P_], __ATOMIC_RELAXED, __HIP_MEMORY_SCOPE_WORKGROUP) != (TT)) {} \
        asm volatile("" ::: "memory"); \
        const float4 u4_ = *reinterpret_cast<const float4*>(&r3v[w - 1][P_][y0]); \
        gu_[0] = u4_.x; gu_[1] = u4_.y; gu_[2] = u4_.z; gu_[3] = u4_.w; \
    } \
    if (w == WAVES - 1) { \
        if (s == NSLAB - 1) { gd_[0] = gd_[1] = gd_[2] = gd_[3] = 0.f; } \
        else GPOLL(gd_, 1, s, P_, TT); \
    } else { \
        while (__hip_atomic_load(&r0t[w + 1][P_], __ATOMIC_RELAXED, __HIP_MEMORY_SCOPE_WORKGROUP) != (TT)) {} \
        asm volatile("" ::: "memory"); \
        const float4 d4_ = *reinterpret_cast<const float4*>(&r0v[w + 1][P_][y0]); \
        gd_[0] = d4_.x; gd_[1] = d4_.y; gd_[2] = d4_.z; gd_[3] = d4_.w; \
    } \
    /* boundary rows first */ \
    ROWC(H1, H2, 0, gu_, H1[1]); \
    ROWC(H1, H2, 3, H1[2], gd_); \
    SRCP(H2, 0, TT); \
    SRCP(H2, 3, TT); \
    /* publish: vals, drain DS, then tags (in-order DS => tag implies vals) */ \
    if (w > 0) \
        *reinterpret_cast<float4*>(&r0v[w][Q_][y0]) = make_float4(H2[0][0], H2[0][1], H2[0][2], H2[0][3]); \
    if (w < WAVES - 1) \
        *reinterpret_cast<float4*>(&r3v[w][Q_][y0]) = make_float4(H2[3][0], H2[3][1], H2[3][2], H2[3][3]); \
    asm volatile("s_waitcnt lgkmcnt(0)" ::: "memory"); \
    if (l == 0) { \
        if (w > 0) \
            __hip_atomic_store(&r0t[w][Q_], (TT) + 1, __ATOMIC_RELAXED, __HIP_MEMORY_SCOPE_WORKGROUP); \
        if (w < WAVES - 1) \
            __hip_atomic_store(&r3t[w][Q_], (TT) + 1, __ATOMIC_RELAXED, __HIP_MEMORY_SCOPE_WORKGROUP); \
    } \
    if (w == 0 && s > 0)                 GPUB(1, s - 1, Q_, (TT) + 1, H2[0]); \
    if (w == WAVES - 1 && s < NSLAB - 1) GPUB(0, s,     Q_, (TT) + 1, H2[3]); \
    /* interior rows overlap neighbors' consumption */ \
    ROWC(H1, H2, 1, H1[0], H1[2]); \
    ROWC(H1, H2, 2, H1[1], H1[3]); \
    SRCP(H2, 1, TT); \
    SRCP(H2, 2, TT); \
} while (0)

__launch_bounds__(THREADS, 2)
__global__ void wave_multi(const float* __restrict__ xin,
                           const float* __restrict__ cin,
                           const float* __restrict__ bin,
                           const int* __restrict__ pxp,
                           const int* __restrict__ pyp,
                           const int* __restrict__ sxp,
                           const int* __restrict__ syp,
                           float* __restrict__ out)
{
    const int blk = blockIdx.x;
    // XCD colocation: blk%8 = XCD (round-robin dispatch). Put all slabs of a
    // batch on one XCD: b%8 == blk%8.
    const int xcd = blk & 7;
    const int m   = blk >> 3;         // 0..15
    const int s   = m & 7;            // slab: rows [s*32, s*32+32)
    const int b   = xcd + ((m >> 3) << 3);  // batch
    const int tid = threadIdx.x;
    const int w = tid >> 6;           // wave 0..7
    const int l = tid & 63;           // lane
    const int r0 = s * 32 + w * 4;    // global row of tile row 0
    const int y0 = l * 4;             // global col of tile col 0

    __shared__ float xbuf[T_];
    __shared__ float r0v[WAVES][2][NY];   // wave w's row0 values, by parity
    __shared__ float r3v[WAVES][2][NY];   // wave w's row3 values, by parity
    __shared__ int   r0t[WAVES][2];       // tags
    __shared__ int   r3t[WAVES][2];

    for (int i = tid; i < WAVES * 2 * NY; i += THREADS) {
        (&r0v[0][0][0])[i] = 0.f;
        (&r3v[0][0][0])[i] = 0.f;
    }
    if (tid < WAVES * 2) {
        const int w_ = tid >> 1, p_ = tid & 1;
        r0t[w_][p_] = (p_ == 0) ? 0 : -1;   // parity0 holds valid step-0 zeros
        r3t[w_][p_] = (p_ == 0) ? 0 : -1;
    }
    if (tid < T_) xbuf[tid] = xin[b * T_ + tid];

    // state + compressed coefficients: TC = 2*c1, CC = c1*(DT^2*c^2)
    // hn = h2 + TC*(h1-h2) + CC*(s4 - 4*h1)   [c1*c2 == 2*c1 - 1]
    float h1[4][4], h2[4][4], TC[4][4], CC[4][4];
#pragma unroll
    for (int r = 0; r < 4; ++r) {
        const float4 cv = *reinterpret_cast<const float4*>(&cin[(r0 + r) * NY + y0]);
        const float4 bv = *reinterpret_cast<const float4*>(&bin[(r0 + r) * NY + y0]);
        const float cvv[4] = {cv.x, cv.y, cv.z, cv.w};
        const float bvv[4] = {bv.x, bv.y, bv.z, bv.w};
#pragma unroll
        for (int j = 0; j < 4; ++j) {
            const float c1  = 1.0f / (1.0f + 0.25f * bvv[j]);
            const float csq = 0.25f * cvv[j] * cvv[j];
            TC[r][j] = 2.0f * c1;
            CC[r][j] = c1 * csq;
            h1[r][j] = 0.f;
            h2[r][j] = 0.f;
        }
    }

    const int sx = sxp[0], sy = syp[0];
    const bool srcHere = (sx >= r0 && sx < r0 + 4 && sy >= y0 && sy < y0 + 4);
    const int  src_r = sx - r0, src_c = sy - y0;
    bool pHere[NP];
    int  pr[NP], pc[NP];
#pragma unroll
    for (int q = 0; q < NP; ++q) {
        const int pxx = pxp[q], pyy = pyp[q];
        pHere[q] = (pxx >= r0 && pxx < r0 + 4 && pyy >= y0 && pyy < y0 + 4);
        pr[q] = pxx - r0;
        pc[q] = pyy - y0;
    }

    __syncthreads();   // the only barrier: LDS init

#pragma unroll 1
    for (int t = 0; t < T_; t += 2) {
        SUB(h1, h2, t,     0, 1);   // h^{t+1} -> h2
        SUB(h2, h1, t + 1, 1, 0);   // h^{t+2} -> h1
    }
}

extern "C" void kernel_launch(void* const* d_in, const int* in_sizes, int n_in,
                              void* d_out, int out_size, void* d_ws, size_t ws_size,
                              hipStream_t stream)
{
    const float* x  = (const float*)d_in[0];
    const float* c  = (const float*)d_in[1];
    const float* bb = (const float*)d_in[2];
    const int*   px = (const int*)d_in[3];
    const int*   py = (const int*)d_in[4];
    const int*   sx = (const int*)d_in[5];
    const int*   sy = (const int*)d_in[6];
    float* out = (float*)d_out;

    const int words = 2 * B_ * NIF * 2 * 4 * 64;
    reset_halo<<<(words + 255) / 256, 256, 0, stream>>>();

    void* args[] = { (void*)&x, (void*)&c, (void*)&bb, (void*)&px, (void*)&py,
                     (void*)&sx, (void*)&sy, (void*)&out };
    hipLaunchCooperativeKernel(reinterpret_cast<void*>(wave_multi),
                               dim3(B_ * NSLAB), dim3(THREADS), args, 0, stream);
}